// Round 13
// baseline (108.207 us; speedup 1.0000x reference)
//
#include <hip/hip_runtime.h>
#include <math.h>

// B=16,H=14,W=14,D=512, L=32, HID=512, A=512. fp32 in/out; bf16 inside MFMA GEMMs.
// R13: 3 kernels, no global sync. gemm1 -> mid (online-softmax fused scores+ctx,
// maps read ONCE) -> gemm2 (bf16 A, fused epilogue). Dbuf K-halves in the gemms.

typedef __attribute__((ext_vector_type(8))) short short8;
typedef __attribute__((ext_vector_type(4))) float f32x4;

__device__ __forceinline__ unsigned f2bf_u(float x) {
    union { float f; unsigned u; } c; c.f = x;
    return (c.u + 0x7FFFu + ((c.u >> 16) & 1u)) >> 16;   // RNE, finite inputs
}
__device__ __forceinline__ unsigned pack2(float lo, float hi) {
    return f2bf_u(lo) | (f2bf_u(hi) << 16);
}
__device__ __forceinline__ uint4 pack8(const float4 a, const float4 b) {
    uint4 r;
    r.x = pack2(a.x, a.y); r.y = pack2(a.z, a.w);
    r.z = pack2(b.x, b.y); r.w = pack2(b.z, b.w);
    return r;
}

// ---- GEMM: C = A(512,512) · B(512,512)^T + bias[n] [* hmul] ; bf16 MFMA ----
// MODE 0: A fp32 (gemm1). MODE 1: A bf16 (ctx16) + hmul epilogue (gemm2).
// grid 256: tile (m0=(bid>>4)*32, n0=(bid&15)*32). K split in 2 LDS halves;
// half-1 global loads issued before half-0 MFMAs (latency overlap).
// Wave w handles s = w + 4*sl (sl 0..3): sl 0,1 -> half0, sl 2,3 -> half1.
template<int MODE>
__global__ __launch_bounds__(256) void gemm_kernel(
    const float* __restrict__ Af, const unsigned short* __restrict__ Ab,
    const float* __restrict__ Bf, const float* __restrict__ bias,
    const float* __restrict__ hmul, float* __restrict__ C)
{
    __shared__ uint4 As[2][1024];    // 2 x 16KB
    __shared__ uint4 Bs[2][1024];    // 2 x 16KB
    const int tid = threadIdx.x, bid = blockIdx.x;
    const int m0 = (bid >> 4) * 32, n0 = (bid & 15) * 32;

    // slot S (0..1023) of half h: i_loc=S>>6, ln=S&63; t=i_loc&1, s_loc=i_loc>>1;
    // row = t*16 + (ln&15); col8 = (8h+s_loc)*4 + (ln>>4)
    #pragma unroll
    for (int j = 0; j < 4; ++j) {                       // half 0 -> LDS
        const int S = tid + 256 * j;
        const int i = S >> 6, ln = S & 63;
        const int row = (i & 1) * 16 + (ln & 15);
        const int col8 = (i >> 1) * 4 + (ln >> 4);
        uint4 av;
        if (MODE == 0) {
            const float* ap = Af + (size_t)(m0 + row) * 512 + col8 * 8;
            av = pack8(*(const float4*)ap, *(const float4*)(ap + 4));
        } else {
            av = *(const uint4*)(Ab + (size_t)(m0 + row) * 512 + col8 * 8);
        }
        const float* bp = Bf + (size_t)(n0 + row) * 512 + col8 * 8;
        As[0][S] = av;
        Bs[0][S] = pack8(*(const float4*)bp, *(const float4*)(bp + 4));
    }
    __syncthreads();

    // issue half-1 global loads into regs (in flight during half-0 MFMAs)
    float4 raf[4][2], rbf[4][2]; uint4 rab[4];
    #pragma unroll
    for (int j = 0; j < 4; ++j) {
        const int S = tid + 256 * j;
        const int i = S >> 6, ln = S & 63;
        const int row = (i & 1) * 16 + (ln & 15);
        const int col8 = (8 + (i >> 1)) * 4 + (ln >> 4);
        if (MODE == 0) {
            const float* ap = Af + (size_t)(m0 + row) * 512 + col8 * 8;
            raf[j][0] = *(const float4*)ap; raf[j][1] = *(const float4*)(ap + 4);
        } else {
            rab[j] = *(const uint4*)(Ab + (size_t)(m0 + row) * 512 + col8 * 8);
        }
        const float* bp = Bf + (size_t)(n0 + row) * 512 + col8 * 8;
        rbf[j][0] = *(const float4*)bp; rbf[j][1] = *(const float4*)(bp + 4);
    }

    const int w = tid >> 6, ln = tid & 63;
    f32x4 acc[4];                                       // fo = tm*2+tn
    #pragma unroll
    for (int fo = 0; fo < 4; ++fo) acc[fo] = (f32x4){0.f,0.f,0.f,0.f};

    #pragma unroll
    for (int sl = 0; sl < 2; ++sl) {                    // half 0: s = w + 4sl < 8
        const int s_loc = (w + 4 * sl);
        const short8 a0 = *(const short8*)&As[0][(2*s_loc+0)*64 + ln];
        const short8 a1 = *(const short8*)&As[0][(2*s_loc+1)*64 + ln];
        const short8 b0 = *(const short8*)&Bs[0][(2*s_loc+0)*64 + ln];
        const short8 b1 = *(const short8*)&Bs[0][(2*s_loc+1)*64 + ln];
        acc[0] = __builtin_amdgcn_mfma_f32_16x16x32_bf16(a0, b0, acc[0], 0, 0, 0);
        acc[1] = __builtin_amdgcn_mfma_f32_16x16x32_bf16(a0, b1, acc[1], 0, 0, 0);
        acc[2] = __builtin_amdgcn_mfma_f32_16x16x32_bf16(a1, b0, acc[2], 0, 0, 0);
        acc[3] = __builtin_amdgcn_mfma_f32_16x16x32_bf16(a1, b1, acc[3], 0, 0, 0);
    }

    #pragma unroll
    for (int j = 0; j < 4; ++j) {                       // store half 1
        const int S = tid + 256 * j;
        As[1][S] = (MODE == 0) ? pack8(raf[j][0], raf[j][1]) : rab[j];
        Bs[1][S] = pack8(rbf[j][0], rbf[j][1]);
    }
    __syncthreads();

    #pragma unroll
    for (int sl = 0; sl < 2; ++sl) {                    // half 1: s = w + 4(sl+2)
        const int s_loc = (w + 4 * sl);                  // local s within half
        const short8 a0 = *(const short8*)&As[1][(2*s_loc+0)*64 + ln];
        const short8 a1 = *(const short8*)&As[1][(2*s_loc+1)*64 + ln];
        const short8 b0 = *(const short8*)&Bs[1][(2*s_loc+0)*64 + ln];
        const short8 b1 = *(const short8*)&Bs[1][(2*s_loc+1)*64 + ln];
        acc[0] = __builtin_amdgcn_mfma_f32_16x16x32_bf16(a0, b0, acc[0], 0, 0, 0);
        acc[1] = __builtin_amdgcn_mfma_f32_16x16x32_bf16(a0, b1, acc[1], 0, 0, 0);
        acc[2] = __builtin_amdgcn_mfma_f32_16x16x32_bf16(a1, b0, acc[2], 0, 0, 0);
        acc[3] = __builtin_amdgcn_mfma_f32_16x16x32_bf16(a1, b1, acc[3], 0, 0, 0);
    }
    __syncthreads();                                    // done reading LDS

    float* red = (float*)&As[0][0];                     // 16KB overlay
    #pragma unroll
    for (int fo = 0; fo < 4; ++fo)
        #pragma unroll
        for (int r = 0; r < 4; ++r)
            red[w*1024 + fo*256 + r*64 + ln] = acc[fo][r];
    __syncthreads();
    #pragma unroll
    for (int j = 0; j < 4; ++j) {
        const int o = tid + 256 * j;
        float v = red[o] + red[1024 + o] + red[2048 + o] + red[3072 + o];
        const int fo = o >> 8, r = (o >> 6) & 3, l2 = o & 63;
        // C/D layout: col = lane&15, row = (lane>>4)*4 + reg [m89-verified]
        const int m = m0 + (fo >> 1) * 16 + ((l2 >> 4) << 2) + r;
        const int n = n0 + (fo & 1) * 16 + (l2 & 15);
        v += bias[n];
        if (MODE == 1) v *= hmul[(size_t)m * 512 + n];
        C[(size_t)m * 512 + n] = v;
    }
}

// ---- mid kernel: block (b = bx>>4, s = bx&15) owns l0 = 2s, l0+1 ----
// Online softmax: one pass over 13 chunks of 16 pixels. maps read once.
// Outputs: attn (fp32, d_out) and ctx rows (bf16 -> ws).
__global__ __launch_bounds__(256) void mid_kernel(
    const float* __restrict__ maps, const float* __restrict__ hlin,
    const float* __restrict__ W_rect, const float* __restrict__ b_rect,
    float* __restrict__ attn_out, unsigned int* __restrict__ ctx_out)
{
    const int b = blockIdx.x >> 4, s = blockIdx.x & 15;
    const int l0 = 2 * s;
    const int tid = threadIdx.x;
    const int pi = tid >> 4, k = tid & 15;

    __shared__ float h0[512], h1[512], wv[512];     // 6 KB
    __shared__ float ftile[16 * 516];               // 33 KB
    __shared__ float part0[16 * 16], part1[16 * 16];// 2 KB
    __shared__ float sraw[2 * 208];                 // 1.7 KB (raw scores)
    __shared__ float ep[2 * 16];                    // chunk exp weights
    __shared__ float bc[4];                         // {chunk_max0, chunk_max1, sum0, sum1}

    {
        const float4* H0 = (const float4*)(hlin + ((size_t)b * 32 + l0) * 512);
        const float4* H1 = (const float4*)(hlin + ((size_t)b * 32 + l0 + 1) * 512);
        const float4* WV = (const float4*)W_rect;
        if (tid < 128) { ((float4*)h0)[tid] = H0[tid]; ((float4*)wv)[tid] = WV[tid]; }
        else           { ((float4*)h1)[tid - 128] = H1[tid - 128]; }
    }
    __syncthreads();

    int aoff[8];
    float4 h0r[8], h1r[8], wr[8];
    #pragma unroll
    for (int j = 0; j < 8; ++j) {
        aoff[j] = k * 32 + ((j + k) & 7) * 4;
        h0r[j] = *(const float4*)&h0[aoff[j]];
        h1r[j] = *(const float4*)&h1[aoff[j]];
        wr[j]  = *(const float4*)&wv[aoff[j]];
    }

    const float* mb = maps + (size_t)b * 196 * 512;
    const float br = b_rect[0];
    const int d0 = tid * 2;

    float m0 = -INFINITY, m1 = -INFINITY, ls0 = 0.f, ls1 = 0.f;
    float cA0 = 0.f, cA1 = 0.f, cB0 = 0.f, cB1 = 0.f;

    for (int c = 0; c < 13; ++c) {
        __syncthreads();                               // ftile reuse safety
        #pragma unroll
        for (int it = 0; it < 8; ++it) {
            const int idx = tid + 256 * it;            // 0..2047 float4
            const int r = idx >> 7, c4 = idx & 127;
            int p = c * 16 + r; if (p > 195) p = 195;
            *(float4*)&ftile[r * 516 + c4 * 4] = *(const float4*)(mb + (size_t)p * 512 + c4 * 4);
        }
        __syncthreads();

        // scores partials: thread (pi, k) covers pixel pi, a-slice k*32..+31
        float s0 = 0.f, s1 = 0.f;
        #pragma unroll
        for (int j = 0; j < 8; ++j) {
            const float4 f = *(const float4*)&ftile[pi * 516 + aoff[j]];
            const float4 A = h0r[j], Bv = h1r[j], W = wr[j];
            s0 += fmaxf(f.x + A.x, 0.f) * W.x + fmaxf(f.y + A.y, 0.f) * W.y
                + fmaxf(f.z + A.z, 0.f) * W.z + fmaxf(f.w + A.w, 0.f) * W.w;
            s1 += fmaxf(f.x + Bv.x, 0.f) * W.x + fmaxf(f.y + Bv.y, 0.f) * W.y
                + fmaxf(f.z + Bv.z, 0.f) * W.z + fmaxf(f.w + Bv.w, 0.f) * W.w;
        }
        part0[pi * 16 + k] = s0;
        part1[pi * 16 + k] = s1;
        __syncthreads();

        // wave-0 lanes 0..31: (l = tid>>4, pl = tid&15) finalize + chunk max
        if (tid < 32) {
            const int l = tid >> 4, pl = tid & 15;
            const float* pb = (l ? part1 : part0) + pl * 16;
            const float4 q0 = *(const float4*)pb,       q1 = *(const float4*)(pb + 4);
            const float4 q2 = *(const float4*)(pb + 8), q3 = *(const float4*)(pb + 12);
            float sc = (q0.x+q0.y+q0.z+q0.w) + (q1.x+q1.y+q1.z+q1.w)
                     + (q2.x+q2.y+q2.z+q2.w) + (q3.x+q3.y+q3.z+q3.w) + br;
            const int p = c * 16 + pl;
            if (p > 195) sc = -INFINITY;
            sraw[l * 208 + p] = sc;
            float mx = sc;
            #pragma unroll
            for (int msk = 1; msk <= 8; msk <<= 1) mx = fmaxf(mx, __shfl_xor(mx, msk));
            if (pl == 0) bc[l] = mx;
        }
        __syncthreads();

        const float nm0 = fmaxf(m0, bc[0]), nm1 = fmaxf(m1, bc[1]);
        if (tid < 32) {
            const int l = tid >> 4, pl = tid & 15;
            const int p = c * 16 + pl;
            const float sc = sraw[l * 208 + p];
            const float e = (p > 195) ? 0.f : __expf(sc - (l ? nm1 : nm0));
            ep[l * 16 + pl] = e;
            float es = e;
            #pragma unroll
            for (int msk = 1; msk <= 8; msk <<= 1) es += __shfl_xor(es, msk);
            if (pl == 0) bc[2 + l] = es;
        }
        __syncthreads();

        const float al0 = __expf(m0 - nm0), al1 = __expf(m1 - nm1);
        ls0 = ls0 * al0 + bc[2];
        ls1 = ls1 * al1 + bc[3];
        m0 = nm0; m1 = nm1;
        cA0 *= al0; cA1 *= al0; cB0 *= al1; cB1 *= al1;
        #pragma unroll
        for (int r = 0; r < 16; ++r) {
            const float2 f = *(const float2*)&ftile[r * 516 + d0];
            const float w0 = ep[r], w1 = ep[16 + r];
            cA0 += w0 * f.x; cA1 += w0 * f.y;
            cB0 += w1 * f.x; cB1 += w1 * f.y;
        }
    }

    const float inv0 = 1.f / ls0, inv1 = 1.f / ls1;
    // ctx rows (bf16 pairs, coalesced 4B/lane)
    ctx_out[((size_t)b * 32 + l0) * 256 + tid]     = pack2(cA0 * inv0, cA1 * inv0);
    ctx_out[((size_t)b * 32 + l0 + 1) * 256 + tid] = pack2(cB0 * inv1, cB1 * inv1);
    // attn rows
    for (int idx = tid; idx < 392; idx += 256) {
        const int l = idx & 1, p = idx >> 1;
        const float sc = sraw[l * 208 + p];
        attn_out[((size_t)b * 32 + l0 + l) * 196 + p] =
            __expf(sc - (l ? m1 : m0)) * (l ? inv1 : inv0);
    }
}

extern "C" void kernel_launch(void* const* d_in, const int* in_sizes, int n_in,
                              void* d_out, int out_size, void* d_ws, size_t ws_size,
                              hipStream_t stream)
{
    const float* maps     = (const float*)d_in[0];
    const float* hiddens  = (const float*)d_in[1];
    const float* W_hidden = (const float*)d_in[2];
    const float* b_hidden = (const float*)d_in[3];
    const float* W_rect   = (const float*)d_in[4];
    const float* b_rect   = (const float*)d_in[5];
    const float* W_co     = (const float*)d_in[6];
    const float* b_co     = (const float*)d_in[7];

    float* out_co   = (float*)d_out;                    // (512,512): hlin temp, then final
    float* out_attn = out_co + (size_t)512 * 512;       // (512,196)
    unsigned int*   ctx32 = (unsigned int*)d_ws;        // (512,512) bf16 = 512 KB
    unsigned short* ctx16 = (unsigned short*)d_ws;

    // 1) hlin = hiddens @ W_hidden^T + b_hidden -> out_co
    hipLaunchKernelGGL((gemm_kernel<0>), dim3(256), dim3(256), 0, stream,
                       hiddens, (const unsigned short*)nullptr, W_hidden, b_hidden,
                       (const float*)nullptr, out_co);
    // 2) scores + online softmax (-> out_attn) + ctx (bf16 -> ws)
    hipLaunchKernelGGL(mid_kernel, dim3(256), dim3(256), 0, stream,
                       maps, out_co, W_rect, b_rect, out_attn, ctx32);
    // 3) out_co = (ctx @ W_co^T + b_co) * hiddens
    hipLaunchKernelGGL((gemm_kernel<1>), dim3(256), dim3(256), 0, stream,
                       (const float*)nullptr, ctx16, W_co, b_co, hiddens, out_co);
}